// Round 2
// baseline (913.942 us; speedup 1.0000x reference)
//
#include <hip/hip_runtime.h>
#include <hip/hip_bf16.h>
#include <stdint.h>

// Problem constants (B=2, NV=25000, C=32, NR=3, ND=16, F=64)
#define NVERT 25000      // vertices per batch
#define NGRP  12500      // groups of 4 vertices (2 pairs)

typedef __bf16  bf16x8 __attribute__((ext_vector_type(8)));
typedef float   f32x16 __attribute__((ext_vector_type(16)));

#define NCHUNK 98                       // 96 conv chunks (r,ch,j) + 2 center chunks
#define BPACK_HALF_USHORT (NCHUNK*512)  // ushorts per f-half fragment pack
#define LDS_B   (NCHUNK*1024)           // 100352 B of B-fragments in LDS (only LDS user now)

__device__ __forceinline__ uint2 pack4(float4 v) {
  union { __hip_bfloat162 h; unsigned u; } a, b;
  a.h = __float22bfloat162_rn(float2{v.x, v.y});
  b.h = __float22bfloat162_rn(float2{v.z, v.w});
  return uint2{a.u, b.u};
}

__device__ __forceinline__ bf16x8 mkfrag(float4 a, float4 b) {
  union { bf16x8 v; uint2 u[2]; } t;
  t.u[0] = pack4(a);   // elems 0..3
  t.u[1] = pack4(b);   // elems 4..7
  return t.v;
}

__device__ __forceinline__ unsigned short f2bf(float f) {
  unsigned int u = __float_as_uint(f);
  u += 0x7FFFu + ((u >> 16) & 1u);   // round-to-nearest-even
  return (unsigned short)(u >> 16);
}

// lane-rotate within 16-lane rows (row_ror:15): dst[i] = src[(i+1)&15] — verified (R1+ pass)
__device__ __forceinline__ bf16x8 rot16(bf16x8 x) {
  union { bf16x8 v; int i[4]; } u;
  u.v = x;
#pragma unroll
  for (int k = 0; k < 4; ++k)
    u.i[k] = __builtin_amdgcn_update_dpp(0, u.i[k], 0x12F, 0xF, 0xF, true);
  return u.v;
}

// Pack kernel (3,16,32,64) + center_kernel (32,64) into MFMA B-fragment order, bf16.
// Layout: bpack[fh(2)][kc(98)][lane(64)][i(8)] ushort.
// kc = (r*2+ch)*16 + j for conv; kc = 96+ch for center. B[k][n]: n=lane&31, k=8*(lane>>5)+i, c=ch*16+k.
__global__ __launch_bounds__(256) void prepack_kernel(
    const float* __restrict__ kern, const float* __restrict__ ckern,
    unsigned short* __restrict__ bpack)
{
  int tid = blockIdx.x*256 + threadIdx.x;
  if (tid >= 2*BPACK_HALF_USHORT) return;
  int fh  = tid / BPACK_HALF_USHORT;
  int rem = tid - fh*BPACK_HALF_USHORT;
  int kc  = rem >> 9;
  int e   = rem & 511;
  int l   = e >> 3, i = e & 7;
  int f   = fh*32 + (l & 31);
  int kk  = ((l >> 5) << 3) + i;
  float v;
  if (kc < 96) {
    int r = kc >> 5, ch = (kc >> 4) & 1, j = kc & 15;
    int c = ch*16 + kk;
    v = kern[((r*16 + j)*32 + c)*64 + f];
  } else {
    int c = (kc - 96)*16 + kk;
    v = ckern[c*64 + f];
  }
  bpack[tid] = f2bf(v);
}

// ---- Direct-gather, barrier-free structure ----
// Each wave independently handles group g (4 vertices = 2 pairs), FULL K=32:
// gathers A fragments straight from y (fp32->bf16 cvt, no LDS staging), rotates
// in-register (DPP), accumulates acc0 (pair0) / acc1 (pair1), own epilogue.
// LDS holds only the B-pack; the single barrier is after the B-pack copy.

// Gather one conv pass's fp32 A data: per pair p, row em[p*3+rr]; lane (q,d,hi)
// reads bytes [hi*32, hi*32+32) (c = hi*8..+7) and [64+hi*32, ..) (c = 16+hi*8..+7).
#define LOADR(dst, E, rr)                                                      \
  {                                                                            \
    _Pragma("unroll")                                                          \
    for (int p = 0; p < 2; ++p) {                                              \
      const int2 e = E[p*3 + (rr)];                                            \
      const int rowi = e.y + (e.x ? NVERT : 0);                                \
      const char* yb = (const char*)y + (size_t)rowi*128 + hi*32;              \
      dst[p*4+0] = *(const float4*)(yb);                                       \
      dst[p*4+1] = *(const float4*)(yb + 16);                                  \
      dst[p*4+2] = *(const float4*)(yb + 64);                                  \
      dst[p*4+3] = *(const float4*)(yb + 80);                                  \
    }                                                                          \
  }

// Center rows: output vertex gg*4 + 2p + q, duplicated across d lanes (L1 bcast)
#define LOADC(dst, gg)                                                         \
  {                                                                            \
    _Pragma("unroll")                                                          \
    for (int p = 0; p < 2; ++p) {                                              \
      const char* yb = (const char*)y + (size_t)((gg)*4 + 2*p + q)*128 + hi*32;\
      dst[p*4+0] = *(const float4*)(yb);                                       \
      dst[p*4+1] = *(const float4*)(yb + 16);                                  \
      dst[p*4+2] = *(const float4*)(yb + 64);                                  \
      dst[p*4+3] = *(const float4*)(yb + 80);                                  \
    }                                                                          \
  }

#define CVT4(st)                                                               \
  a00 = mkfrag(st[0], st[1]); a01 = mkfrag(st[2], st[3]);                      \
  a10 = mkfrag(st[4], st[5]); a11 = mkfrag(st[6], st[7]);

// One r-pass, full K=32: 2 B reads per j shared by both pairs (4 MFMA), chains
// interleaved acc0/acc1 per B fragment.
#define PASS2(rr)                                                              \
  {                                                                            \
    const char* bp = bbase + (size_t)(rr)*32768;                               \
    _Pragma("unroll")                                                          \
    for (int j = 0; j < 16; ++j) {                                             \
      const bf16x8 b0 = *(const bf16x8*)(bp + (size_t)j*1024);                 \
      const bf16x8 b1 = *(const bf16x8*)(bp + (size_t)j*1024 + 16384);         \
      acc0 = __builtin_amdgcn_mfma_f32_32x32x16_bf16(a00, b0, acc0, 0, 0, 0);  \
      acc1 = __builtin_amdgcn_mfma_f32_32x32x16_bf16(a10, b0, acc1, 0, 0, 0);  \
      acc0 = __builtin_amdgcn_mfma_f32_32x32x16_bf16(a01, b1, acc0, 0, 0, 0);  \
      acc1 = __builtin_amdgcn_mfma_f32_32x32x16_bf16(a11, b1, acc1, 0, 0, 0);  \
      if (j < 15) { a00 = rot16(a00); a01 = rot16(a01);                        \
                    a10 = rot16(a10); a11 = rot16(a11); }                      \
    }                                                                          \
  }

__global__ __launch_bounds__(512, 2) void conv_kernel(
    const float* __restrict__ y,
    const int*   __restrict__ em,     // exp_map int pairs (b,v), flat (u*48 + r*16+dd)
    const float* __restrict__ bias,
    const unsigned short* __restrict__ bpack,
    float* __restrict__ out)
{
  extern __shared__ __align__(16) char smem[];
  const int fh  = blockIdx.x & 1;     // which 32-wide f half
  const int bl  = blockIdx.x >> 1;    // 0..127
  const int tid = threadIdx.x;
  const int w   = tid >> 6;           // wave 0..7
  const int l   = tid & 63;

  // ---- stage this f-half's B fragments into LDS (once per block) ----
  {
    const uint4* src = (const uint4*)(bpack + (size_t)fh * BPACK_HALF_USHORT);
    uint4* dst = (uint4*)smem;
    for (int idx = tid; idx < LDS_B/16; idx += 512) dst[idx] = src[idx];
  }
  __syncthreads();   // the ONLY barrier — B-pack is read-only afterwards

  const char* bbase = smem + (size_t)l * 16;    // canonical fragment read: 0 conflicts
  const float biasv = bias[fh*32 + (l & 31)];
  const int q  = (l >> 4) & 1;        // A-operand: vertex within pair (m>>4)
  const int d  = l & 15;              // A-operand: direction (m&15)
  const int hi = l >> 5;              // A/B operand: k-half selector

  const int wf = bl*8 + w;            // wave id within this f-half: 0..1023
  int g = wf;                          // group stride 1024, NGRP=12500 -> 12-13 iters

  // ---- prologue: em(g) then r=0 gather into stA ----
  int2 ec[6], en[6];
  {
    const char* eb = (const char*)em + ((size_t)(g*4 + q)*48 + d)*8;
#pragma unroll
    for (int p = 0; p < 2; ++p)
#pragma unroll
      for (int r = 0; r < 3; ++r)
        ec[p*3 + r] = *(const int2*)(eb + p*768 + r*128);
  }
  float4 stA[8], stB[8];
  LOADR(stA, ec, 0)

  for (;;) {
    const int gn = g + 1024;
    const bool vnext = (gn < NGRP);
    const int gp = vnext ? gn : g;    // clamped prefetch target (results unused on last iter)

    // em prefetch for next group (lands during passes 0-1)
    {
      const char* eb = (const char*)em + ((size_t)(gp*4 + q)*48 + d)*8;
#pragma unroll
      for (int p = 0; p < 2; ++p)
#pragma unroll
        for (int r = 0; r < 3; ++r)
          en[p*3 + r] = *(const int2*)(eb + p*768 + r*128);
    }

    f32x16 acc0, acc1;
#pragma unroll
    for (int k = 0; k < 16; ++k) { acc0[k] = 0.f; acc1[k] = 0.f; }

    bf16x8 a00, a01, a10, a11;

    // pass r=0: cvt stA, issue r=1 gather, compute
    CVT4(stA)
    LOADR(stB, ec, 1)
    PASS2(0)

    // pass r=1: cvt stB, issue r=2 gather, compute
    CVT4(stB)
    LOADR(stA, ec, 2)
    PASS2(1)

    // pass r=2: cvt stA, issue center(g) + next-iter r=0 gathers, compute
    CVT4(stA)
    LOADC(stB, g)
    LOADR(stA, en, 0)        // next iteration's r=0 (clamped-safe on last iter)
    PASS2(2)

    // center term (broadcast over d): 4 MFMAs
    {
      const bf16x8 c00 = mkfrag(stB[0], stB[1]);
      const bf16x8 c01 = mkfrag(stB[2], stB[3]);
      const bf16x8 c10 = mkfrag(stB[4], stB[5]);
      const bf16x8 c11 = mkfrag(stB[6], stB[7]);
      const bf16x8 bc0 = *(const bf16x8*)(bbase + 96*1024);
      const bf16x8 bc1 = *(const bf16x8*)(bbase + 97*1024);
      acc0 = __builtin_amdgcn_mfma_f32_32x32x16_bf16(c00, bc0, acc0, 0, 0, 0);
      acc1 = __builtin_amdgcn_mfma_f32_32x32x16_bf16(c10, bc0, acc1, 0, 0, 0);
      acc0 = __builtin_amdgcn_mfma_f32_32x32x16_bf16(c01, bc1, acc0, 0, 0, 0);
      acc1 = __builtin_amdgcn_mfma_f32_32x32x16_bf16(c11, bc1, acc1, 0, 0, 0);
    }

    // ---- epilogue: full fp32 sums already in-register (no exchange, no bf16 loss)
    // C/D layout (m74/m101): n = lane&31, m = (reg&3)+8*(reg>>2)+4*(lane>>5).
    // regs 0..7 -> vertex 0 of pair, regs 8..15 -> vertex 1; shfl_xor 32 merges hi-halves of d.
    {
      float m0 = acc0[0], m1 = acc0[8];
#pragma unroll
      for (int k = 1; k < 8; ++k) { m0 = fmaxf(m0, acc0[k]); m1 = fmaxf(m1, acc0[8+k]); }
      m0 = fmaxf(m0, __shfl_xor(m0, 32, 64));
      m1 = fmaxf(m1, __shfl_xor(m1, 32, 64));
      float v = (hi ? m1 : m0) + biasv;
      out[(size_t)(g*4 + hi)*64 + fh*32 + (l & 31)] = fmaxf(v, 0.f);
    }
    {
      float m0 = acc1[0], m1 = acc1[8];
#pragma unroll
      for (int k = 1; k < 8; ++k) { m0 = fmaxf(m0, acc1[k]); m1 = fmaxf(m1, acc1[8+k]); }
      m0 = fmaxf(m0, __shfl_xor(m0, 32, 64));
      m1 = fmaxf(m1, __shfl_xor(m1, 32, 64));
      float v = (hi ? m1 : m0) + biasv;
      out[(size_t)(g*4 + 2 + hi)*64 + fh*32 + (l & 31)] = fmaxf(v, 0.f);
    }

    if (!vnext) break;
    g = gn;
#pragma unroll
    for (int i = 0; i < 6; ++i) ec[i] = en[i];
  }
}

extern "C" void kernel_launch(void* const* d_in, const int* in_sizes, int n_in,
                              void* d_out, int out_size, void* d_ws, size_t ws_size,
                              hipStream_t stream) {
  const float* y     = (const float*)d_in[0];
  const int*   em    = (const int*)  d_in[1];
  const float* kern  = (const float*)d_in[2];
  const float* ckern = (const float*)d_in[3];
  const float* bias  = (const float*)d_in[4];
  float* out = (float*)d_out;
  unsigned short* bpack = (unsigned short*)d_ws;   // 200704 bytes used

  // opt in to >64KB dynamic LDS (host-side, graph-capture safe — verified rounds 1-8)
  hipFuncSetAttribute(reinterpret_cast<const void*>(conv_kernel),
                      hipFuncAttributeMaxDynamicSharedMemorySize, LDS_B);

  prepack_kernel<<<(2*BPACK_HALF_USHORT + 255)/256, 256, 0, stream>>>(kern, ckern, bpack);
  conv_kernel<<<256, 512, LDS_B, stream>>>(y, em, bias, bpack, out);
}

// Round 3
// 258.392 us; speedup vs baseline: 3.5370x; 3.5370x over previous
//
#include <hip/hip_runtime.h>
#include <hip/hip_bf16.h>
#include <stdint.h>

// Problem constants (B=2, NV=25000, C=32, NR=3, ND=16, F=64)
#define NVERT 25000      // vertices per batch
#define NGRP  12500      // groups of 4 vertices

typedef __bf16  bf16x8 __attribute__((ext_vector_type(8)));
typedef float   f32x4  __attribute__((ext_vector_type(4)));

// ---- 16x16x32 design: f-quarter (n=16) B-pack, 49 K-chunks (48 conv + 1 center)
#define NKC     49
#define BPACK_Q_USHORT (NKC*512)        // ushorts per f-quarter pack (25088)
#define LDS_B16 (NKC*1024)              // 50176 B of B-fragments in LDS
#define ROWB    64                      // patch row: 32 bf16, no pad (bank-uniform reads)
#define VST     (49*ROWB)               // per-vertex patch: 48 dir-rows + 1 center = 3136 B
#define WST     (4*VST)                 // per-wave patch: 4 vertices = 12544 B
#define LDS_TOT (LDS_B16 + 8*WST)       // 150528 <= 163840; 1 block/CU, 2 waves/SIMD

__device__ __forceinline__ uint2 pack4(float4 v) {
  union { __hip_bfloat162 h; unsigned u; } a, b;
  a.h = __float22bfloat162_rn(float2{v.x, v.y});
  b.h = __float22bfloat162_rn(float2{v.z, v.w});
  return uint2{a.u, b.u};
}

__device__ __forceinline__ unsigned short f2bf(float f) {
  unsigned int u = __float_as_uint(f);
  u += 0x7FFFu + ((u >> 16) & 1u);   // round-to-nearest-even
  return (unsigned short)(u >> 16);
}

// lane-rotate within 16-lane rows (row_ror:15): dst[i] = src[(i+1)&15] — harness-verified
__device__ __forceinline__ bf16x8 rot16(bf16x8 x) {
  union { bf16x8 v; int i[4]; } u;
  u.v = x;
#pragma unroll
  for (int k = 0; k < 4; ++k)
    u.i[k] = __builtin_amdgcn_update_dpp(0, u.i[k], 0x12F, 0xF, 0xF, true);
  return u.v;
}

// Pack kernel (3,16,32,64) + center_kernel (32,64) into 16x16x32 MFMA B-fragment order.
// Layout: bpack[fq(4)][kc(49)][lane(64)][i(8)] ushort.
// kc = r*16 + j for conv; kc = 48 for center. B[k][n]: n = lane&15, k = c = 8*(lane>>4)+i.
// (A staging uses the same c(lane,i) function, so the pairing is mapping-robust.)
__global__ __launch_bounds__(256) void prepack_kernel(
    const float* __restrict__ kern, const float* __restrict__ ckern,
    unsigned short* __restrict__ bpack)
{
  int tid = blockIdx.x*256 + threadIdx.x;
  if (tid >= 4*BPACK_Q_USHORT) return;
  int fq  = tid / BPACK_Q_USHORT;
  int rem = tid - fq*BPACK_Q_USHORT;
  int kc  = rem >> 9;
  int e   = rem & 511;
  int l   = e >> 3, i = e & 7;
  int f   = fq*16 + (l & 15);
  int c   = ((l >> 4) << 3) + i;
  float v;
  if (kc < 48) {
    int r = kc >> 4, j = kc & 15;
    v = kern[((r*16 + j)*32 + c)*64 + f];
  } else {
    v = ckern[c*64 + f];
  }
  bpack[tid] = f2bf(v);
}

// One r-pass: B fragment per j (canonical lane*16 read, 0 conflicts), 4 MFMA per
// B-read (one per vertex), A rotated in-register over the direction dim (DPP).
#define PASS16(rr)                                                             \
  {                                                                            \
    const char* bp = bbase + (size_t)(rr)*16384;                               \
    _Pragma("unroll")                                                          \
    for (int j = 0; j < 16; ++j) {                                             \
      const bf16x8 b = *(const bf16x8*)(bp + (size_t)j*1024);                  \
      acc0 = __builtin_amdgcn_mfma_f32_16x16x32_bf16(a0, b, acc0, 0, 0, 0);    \
      acc1 = __builtin_amdgcn_mfma_f32_16x16x32_bf16(a1, b, acc1, 0, 0, 0);    \
      acc2 = __builtin_amdgcn_mfma_f32_16x16x32_bf16(a2, b, acc2, 0, 0, 0);    \
      acc3 = __builtin_amdgcn_mfma_f32_16x16x32_bf16(a3, b, acc3, 0, 0, 0);    \
      if (j < 15) { a0 = rot16(a0); a1 = rot16(a1);                            \
                    a2 = rot16(a2); a3 = rot16(a3); }                          \
    }                                                                          \
  }

// A-reads for pass rr: one b128 per vertex; addr = d*64 + g4*16 is a permuted-
// contiguous 1KB read across the wave -> bank-uniform, conflict-free.
#define LDA16(rr)                                                              \
  a0 = *(const bf16x8*)(pb0 + (rr)*1024);                                      \
  a1 = *(const bf16x8*)(pb1 + (rr)*1024);                                      \
  a2 = *(const bf16x8*)(pb2 + (rr)*1024);                                      \
  a3 = *(const bf16x8*)(pb3 + (rr)*1024);

__global__ __launch_bounds__(512, 2) void conv_kernel(
    const float* __restrict__ y,
    const int*   __restrict__ em,     // exp_map int pairs (b,v), flat (u*48 + r*16+dd)
    const float* __restrict__ bias,
    const unsigned short* __restrict__ bpack,
    float* __restrict__ out)
{
  extern __shared__ __align__(16) char smem[];
  const int fq  = blockIdx.x & 3;     // which 16-wide f quarter
  const int bl  = blockIdx.x >> 2;    // 0..63
  const int tid = threadIdx.x;
  const int w   = tid >> 6;           // wave 0..7
  const int l   = tid & 63;

  // ---- stage this f-quarter's B fragments into LDS (once per block) ----
  {
    const uint4* src = (const uint4*)(bpack + (size_t)fq * BPACK_Q_USHORT);
    uint4* dst = (uint4*)smem;
    for (int idx = tid; idx < LDS_B16/16; idx += 512) dst[idx] = src[idx];
  }
  __syncthreads();   // the ONLY barrier — B-pack is read-only afterwards

  const char* bbase = smem + (size_t)l * 16;     // canonical fragment read
  char* const pbase = smem + LDS_B16 + w*WST;    // this wave's PRIVATE patch
  const int d  = l & 15;              // A-operand: direction row (m)
  const int g4 = l >> 4;              // A/B operand: k-group selector
  const float biasv = bias[fq*16 + d];

  // staging lane roles (R0-verified pattern: 8 lanes x 16B cover a 128B fp32 row)
  const int rsl = l >> 3, cp = l & 7;
  char* const sbase = pbase + rsl*ROWB + cp*8;

  // A-read bases (r=0); pass rr adds rr*1024; center row at +3072
  const char* pb0 = pbase + 0*VST + d*ROWB + g4*16;
  const char* pb1 = pbase + 1*VST + d*ROWB + g4*16;
  const char* pb2 = pbase + 2*VST + d*ROWB + g4*16;
  const char* pb3 = pbase + 3*VST + d*ROWB + g4*16;

  const int wt = bl*8 + w;            // wave-task id within this f-quarter: 0..511
  int g = wt;

  // ---- prologue: stage group g into this wave's private patch ----
  {
    const char* eb = (const char*)em + ((size_t)(g*4)*48 + rsl)*8;
    int2 e0[24];
#pragma unroll
    for (int it = 0; it < 24; ++it)
      e0[it] = *(const int2*)(eb + (it & 3)*384 + (it >> 2)*64);
    uint2 sv[24];
#pragma unroll
    for (int it = 0; it < 24; ++it) {
      const int rowi = e0[it].y + (e0[it].x ? NVERT : 0);
      sv[it] = pack4(*(const float4*)((const char*)y + (size_t)rowi*128 + cp*16));
    }
    uint2 svc;
    if (l < 32)
      svc = pack4(*(const float4*)((const char*)y + (size_t)(g*4 + rsl)*128 + cp*16));
#pragma unroll
    for (int it = 0; it < 24; ++it)
      *(uint2*)(sbase + (it & 3)*VST + (it >> 2)*512) = sv[it];
    if (l < 32)
      *(uint2*)(pbase + rsl*VST + 3072 + cp*8) = svc;
  }

  for (; g < NGRP; g += 512) {
    const int gn = g + 512;
    const bool vnext = (gn < NGRP);

    f32x4 acc0, acc1, acc2, acc3;
#pragma unroll
    for (int k = 0; k < 4; ++k) { acc0[k]=0.f; acc1[k]=0.f; acc2[k]=0.f; acc3[k]=0.f; }

    bf16x8 a0, a1, a2, a3;

    // ---- em prefetch for gn (latency hidden under pass 0) ----
    int2 e[24];
    if (vnext) {
      const char* eb = (const char*)em + ((size_t)(gn*4)*48 + rsl)*8;
#pragma unroll
      for (int it = 0; it < 24; ++it)
        e[it] = *(const int2*)(eb + (it & 3)*384 + (it >> 2)*64);
    }

    LDA16(0)
    PASS16(0)

    // ---- y gathers for gn, batch 1 (coalesced row reads, pack on arrival) ----
    uint2 sv[24], svc;
    if (vnext) {
#pragma unroll
      for (int it = 0; it < 12; ++it) {
        const int rowi = e[it].y + (e[it].x ? NVERT : 0);
        sv[it] = pack4(*(const float4*)((const char*)y + (size_t)rowi*128 + cp*16));
      }
    }

    LDA16(1)
    PASS16(1)

    // ---- y gathers batch 2 + center rows ----
    if (vnext) {
#pragma unroll
      for (int it = 12; it < 24; ++it) {
        const int rowi = e[it].y + (e[it].x ? NVERT : 0);
        sv[it] = pack4(*(const float4*)((const char*)y + (size_t)rowi*128 + cp*16));
      }
      if (l < 32)
        svc = pack4(*(const float4*)((const char*)y + (size_t)(gn*4 + rsl)*128 + cp*16));
    }

    LDA16(2)
    PASS16(2)

    // ---- center term: A rows broadcast over d (16B broadcast reads) ----
    {
      a0 = *(const bf16x8*)(pbase + 0*VST + 3072 + g4*16);
      a1 = *(const bf16x8*)(pbase + 1*VST + 3072 + g4*16);
      a2 = *(const bf16x8*)(pbase + 2*VST + 3072 + g4*16);
      a3 = *(const bf16x8*)(pbase + 3*VST + 3072 + g4*16);
      const bf16x8 bc = *(const bf16x8*)(bbase + 48*1024);
      acc0 = __builtin_amdgcn_mfma_f32_16x16x32_bf16(a0, bc, acc0, 0, 0, 0);
      acc1 = __builtin_amdgcn_mfma_f32_16x16x32_bf16(a1, bc, acc1, 0, 0, 0);
      acc2 = __builtin_amdgcn_mfma_f32_16x16x32_bf16(a2, bc, acc2, 0, 0, 0);
      acc3 = __builtin_amdgcn_mfma_f32_16x16x32_bf16(a3, bc, acc3, 0, 0, 0);
    }

    // ---- epilogue: C/D 16x16 (m89): col = lane&15 = f, row = (lane>>4)*4+reg = dd.
    // max over dd = max over 4 regs then over lane-groups (xor 16, 32); +bias, relu.
    {
      float m0 = fmaxf(fmaxf(acc0[0], acc0[1]), fmaxf(acc0[2], acc0[3]));
      float m1 = fmaxf(fmaxf(acc1[0], acc1[1]), fmaxf(acc1[2], acc1[3]));
      float m2 = fmaxf(fmaxf(acc2[0], acc2[1]), fmaxf(acc2[2], acc2[3]));
      float m3 = fmaxf(fmaxf(acc3[0], acc3[1]), fmaxf(acc3[2], acc3[3]));
      m0 = fmaxf(m0, __shfl_xor(m0, 16)); m0 = fmaxf(m0, __shfl_xor(m0, 32));
      m1 = fmaxf(m1, __shfl_xor(m1, 16)); m1 = fmaxf(m1, __shfl_xor(m1, 32));
      m2 = fmaxf(m2, __shfl_xor(m2, 16)); m2 = fmaxf(m2, __shfl_xor(m2, 32));
      m3 = fmaxf(m3, __shfl_xor(m3, 16)); m3 = fmaxf(m3, __shfl_xor(m3, 32));
      const float sel = (g4 == 0) ? m0 : (g4 == 1) ? m1 : (g4 == 2) ? m2 : m3;
      out[(size_t)(g*4 + g4)*64 + fq*16 + d] = fmaxf(sel + biasv, 0.f);
    }

    // ---- stage gn into this wave's private patch (all A-reads of g are done;
    // same-wave DS ordering + compiler alias tracking make this barrier-free) ----
    if (vnext) {
#pragma unroll
      for (int it = 0; it < 24; ++it)
        *(uint2*)(sbase + (it & 3)*VST + (it >> 2)*512) = sv[it];
      if (l < 32)
        *(uint2*)(pbase + rsl*VST + 3072 + cp*8) = svc;
    }
  }
}

extern "C" void kernel_launch(void* const* d_in, const int* in_sizes, int n_in,
                              void* d_out, int out_size, void* d_ws, size_t ws_size,
                              hipStream_t stream) {
  const float* y     = (const float*)d_in[0];
  const int*   em    = (const int*)  d_in[1];
  const float* kern  = (const float*)d_in[2];
  const float* ckern = (const float*)d_in[3];
  const float* bias  = (const float*)d_in[4];
  float* out = (float*)d_out;
  unsigned short* bpack = (unsigned short*)d_ws;   // 200704 bytes used

  // opt in to >64KB dynamic LDS (host-side, graph-capture safe — verified rounds 1-8)
  hipFuncSetAttribute(reinterpret_cast<const void*>(conv_kernel),
                      hipFuncAttributeMaxDynamicSharedMemorySize, LDS_TOT);

  prepack_kernel<<<(4*BPACK_Q_USHORT + 255)/256, 256, 0, stream>>>(kern, ckern, bpack);
  conv_kernel<<<256, 512, LDS_TOT, stream>>>(y, em, bias, bpack, out);
}